// Round 7
// baseline (354.533 us; speedup 1.0000x reference)
//
#include <hip/hip_runtime.h>

#define NN 20000   // nodes
#define EE 640000  // edges
#define CAP 2048   // LDS edge-cache (int2) = 16 KB -> no occupancy throttle
#define WTP 200    // padded k-stride of transposed weight (breaks bank conflict)

typedef __attribute__((ext_vector_type(8))) short short8;
typedef __attribute__((ext_vector_type(4))) float float4v;
typedef __attribute__((ext_vector_type(2))) float float2v;

__device__ __forceinline__ unsigned bf16rn(float x) {
    unsigned u = __float_as_uint(x);
    return (u + 0x7FFFu + ((u >> 16) & 1u)) >> 16;
}
__device__ __forceinline__ unsigned pack2(float a, float b) {
    return bf16rn(a) | (bf16rn(b) << 16);
}
__device__ __forceinline__ float bflo(unsigned u) { return __uint_as_float(u << 16); }
__device__ __forceinline__ float bfhi(unsigned u) { return __uint_as_float(u & 0xFFFF0000u); }

// Fused prep: blocks [0,nCast) cast inputs->xb; [nCast,nCast+79) rowptr;
// [nCast+79, nCast+127) weight fold. All independent -> overlap + fewer launches.
__global__ __launch_bounds__(256) void prep_k(
    const float* __restrict__ inp, unsigned* __restrict__ xb,
    const int* __restrict__ rows, int* __restrict__ rp,
    const float* __restrict__ W, unsigned short* __restrict__ wt,
    int nCast) {
    int bid = blockIdx.x, t = threadIdx.x;
    if (bid < nCast) {
        // inputs[b][n][f] fp32 -> xb[n][b*64+f] bf16; 32B in -> 16B out
        int i = bid * 256 + t;                    // over NN*128 uint4 outputs
        int n = i >> 7, c = i & 127;              // c = b*8 + f8
        int b = c >> 3, f8 = c & 7;
        const float* p = inp + ((size_t)b * NN + n) * 64 + f8 * 8;
        float4 u0 = *(const float4*)(p);
        float4 u1 = *(const float4*)(p + 4);
        uint4 o;
        o.x = pack2(u0.x, u0.y); o.y = pack2(u0.z, u0.w);
        o.z = pack2(u1.x, u1.y); o.w = pack2(u1.z, u1.w);
        *(uint4*)(xb + (size_t)n * 512 + c * 4) = o;
    } else if (bid < nCast + 79) {
        int r = (bid - nCast) * 256 + t;
        if (r > NN) return;
        int lo = 0, hi = EE;
        while (lo < hi) {
            int mid = (lo + hi) >> 1;
            if (rows[mid] < r) lo = mid + 1; else hi = mid;
        }
        rp[r] = lo;
    } else {
        // Wt[o][k'] bf16, k' = m*64+f; Chebyshev fold: m0: W0-W2, m2: 2*W2
        int i = (bid - nCast - 79) * 256 + t;
        if (i >= 64 * 192) return;
        int o = i / 192, kp = i - o * 192;
        int m = kp >> 6, f = kp & 63;
        float w = W[(f * 3 + m) * 64 + o];
        if (m == 0) w -= W[(f * 3 + 2) * 64 + o];
        else if (m == 2) w += w;
        wt[o * WTP + kp] = (unsigned short)bf16rn(w);
    }
}

__device__ __forceinline__ void accum(const uint4& q, int vbits,
                                      float2v& ac0, float2v& ac1,
                                      float2v& ac2, float2v& ac3) {
    float v_ = __int_as_float(vbits);
    float2v vv = {v_, v_};
    float2v p0 = {bflo(q.x), bfhi(q.x)};
    float2v p1 = {bflo(q.y), bfhi(q.y)};
    float2v p2 = {bflo(q.z), bfhi(q.z)};
    float2v p3 = {bflo(q.w), bfhi(q.w)};
    ac0 = __builtin_elementwise_fma(vv, p0, ac0);
    ac1 = __builtin_elementwise_fma(vv, p1, ac1);
    ac2 = __builtin_elementwise_fma(vv, p2, ac2);
    ac3 = __builtin_elementwise_fma(vv, p3, ac3);
}

// dst[n][c] = sum_e v * src[col][c], bf16 in/out.
// XCD-pinned slices: each XCD's 4MB L2 holds one 2.56MB channel-slice.
// ROOFLINE NOTE (rounds 2-5): dur invariant to VALU count (r2), unroll depth
// (r3), forced scheduling (r4); nt loads break L2 allocation (r5: FETCH
// 66->408MB, 2.4x slower). 15.6 TB/s aggregate L2 service = ~79% of random
// 64B-sector channel peak -> this loop is at the L2 ceiling. Do not touch.
__global__ __launch_bounds__(256, 8) void spmm_bf16_k(
    const unsigned* __restrict__ src, const int* __restrict__ cols,
    const float* __restrict__ vals, const int* __restrict__ rp,
    unsigned* __restrict__ dst) {
    __shared__ int2 lcv[CAP];
    int bid = blockIdx.x;
    int xcd = bid & 7, j = bid >> 3;
    int chunk = j % 625;
    int s = xcd + ((j / 625) << 3);
    int t = threadIdx.x;
    int n0 = chunk * 32;
    int eBase = rp[n0];
    int eCap = min(rp[n0 + 32], eBase + CAP);
    for (int i = eBase + t; i < eCap; i += 256)
        lcv[i - eBase] = make_int2(cols[i], __float_as_int(vals[i]));
    __syncthreads();

    int node = n0 + (t >> 3);
    unsigned tOff = (unsigned)(s * 128 + (t & 7) * 16);   // byte offset within row
    const char* sb = (const char*)src;                    // uniform SGPR base
    int e0 = rp[node], e1 = rp[node + 1];
    int eL = min(e1, eCap);
    int le = e0 - eBase, lEnd = eL - eBase;
    float2v ac0 = {0,0}, ac1 = {0,0}, ac2 = {0,0}, ac3 = {0,0};

    int e = le;
    for (; e + 4 <= lEnd; e += 4) {
        int2 c0 = lcv[e],     c1 = lcv[e + 1];
        int2 c2 = lcv[e + 2], c3 = lcv[e + 3];
        uint4 q0 = *(const uint4*)(sb + (((unsigned)c0.x << 11) + tOff));
        uint4 q1 = *(const uint4*)(sb + (((unsigned)c1.x << 11) + tOff));
        uint4 q2 = *(const uint4*)(sb + (((unsigned)c2.x << 11) + tOff));
        uint4 q3 = *(const uint4*)(sb + (((unsigned)c3.x << 11) + tOff));
        accum(q0, c0.y, ac0, ac1, ac2, ac3);
        accum(q1, c1.y, ac0, ac1, ac2, ac3);
        accum(q2, c2.y, ac0, ac1, ac2, ac3);
        accum(q3, c3.y, ac0, ac1, ac2, ac3);
    }
    for (; e < lEnd; ++e) {
        int2 cv = lcv[e];
        uint4 q = *(const uint4*)(sb + (((unsigned)cv.x << 11) + tOff));
        accum(q, cv.y, ac0, ac1, ac2, ac3);
    }
    for (int a = lEnd + eBase; a < e1; ++a) {
        int c = cols[a];
        uint4 q = *(const uint4*)(sb + (((unsigned)c << 11) + tOff));
        accum(q, __float_as_int(vals[a]), ac0, ac1, ac2, ac3);
    }
    uint4 o;
    o.x = pack2(ac0[0], ac0[1]); o.y = pack2(ac1[0], ac1[1]);
    o.z = pack2(ac2[0], ac2[1]); o.w = pack2(ac3[0], ac3[1]);
    *(uint4*)((char*)dst + (size_t)node * 2048 + tOff) = o;
}

// Fused spmm2 + GEMM: block (chunk, s) computes y2 tile = A@y1 for 32 nodes
// x batch s (slice s == batch s in node-major layout), keeps it in regs/LDS,
// then computes out[s][n0..n0+32)[0..64) = [x0|y1|y2] @ Wt + bias directly.
// Deletes the y2 HBM round-trip (40MB write + 41MB read) + one kernel launch.
// LDS: edge cache (16KB) unioned with frag-major A-tile (12KB) -> still 16KB.
// Weights read as B-frags from global (24.6KB region, L1-resident per CU).
__global__ __launch_bounds__(256, 8) void spmm_gemm_k(
    const unsigned* __restrict__ src,      // y1
    const unsigned* __restrict__ xb,       // bf16 x0 (may be null)
    const float* __restrict__ inputs,      // fp32 x0 fallback
    const int* __restrict__ cols, const float* __restrict__ vals,
    const int* __restrict__ rp, const unsigned short* __restrict__ wt,
    const float* __restrict__ bias, float* __restrict__ out) {
    __shared__ union alignas(16) {
        int2 lcv[CAP];                     // 16 KB, edge phase
        unsigned short af[12][64][8];      // 12 KB, frag-major A-tile, epilogue
    } u;
    int bid = blockIdx.x;
    int xcd = bid & 7, j = bid >> 3;
    int chunk = j % 625;
    int s = xcd + ((j / 625) << 3);
    int t = threadIdx.x;
    int n0 = chunk * 32;
    int eBase = rp[n0];
    int eCap = min(rp[n0 + 32], eBase + CAP);
    for (int i2 = eBase + t; i2 < eCap; i2 += 256)
        u.lcv[i2 - eBase] = make_int2(cols[i2], __float_as_int(vals[i2]));
    __syncthreads();

    int node = n0 + (t >> 3);
    unsigned tOff = (unsigned)(s * 128 + (t & 7) * 16);
    const char* sb = (const char*)src;
    int e0 = rp[node], e1 = rp[node + 1];
    int eL = min(e1, eCap);
    int le = e0 - eBase, lEnd = eL - eBase;
    float2v ac0 = {0,0}, ac1 = {0,0}, ac2 = {0,0}, ac3 = {0,0};

    int e = le;
    for (; e + 4 <= lEnd; e += 4) {   // proven 4-deep edge loop (do not touch)
        int2 c0 = u.lcv[e],     c1 = u.lcv[e + 1];
        int2 c2 = u.lcv[e + 2], c3 = u.lcv[e + 3];
        uint4 q0 = *(const uint4*)(sb + (((unsigned)c0.x << 11) + tOff));
        uint4 q1 = *(const uint4*)(sb + (((unsigned)c1.x << 11) + tOff));
        uint4 q2 = *(const uint4*)(sb + (((unsigned)c2.x << 11) + tOff));
        uint4 q3 = *(const uint4*)(sb + (((unsigned)c3.x << 11) + tOff));
        accum(q0, c0.y, ac0, ac1, ac2, ac3);
        accum(q1, c1.y, ac0, ac1, ac2, ac3);
        accum(q2, c2.y, ac0, ac1, ac2, ac3);
        accum(q3, c3.y, ac0, ac1, ac2, ac3);
    }
    for (; e < lEnd; ++e) {
        int2 cv = u.lcv[e];
        uint4 q = *(const uint4*)(sb + (((unsigned)cv.x << 11) + tOff));
        accum(q, cv.y, ac0, ac1, ac2, ac3);
    }
    for (int a2 = lEnd + eBase; a2 < e1; ++a2) {
        int c = cols[a2];
        uint4 q = *(const uint4*)(sb + (((unsigned)c << 11) + tOff));
        accum(q, __float_as_int(vals[a2]), ac0, ac1, ac2, ac3);
    }
    uint4 o;
    o.x = pack2(ac0[0], ac0[1]); o.y = pack2(ac1[0], ac1[1]);
    o.z = pack2(ac2[0], ac2[1]); o.w = pack2(ac3[0], ac3[1]);

    // ---- stage A = [x0|y1|y2] (32 nodes x 192 bf16, batch s) in frag order.
    // thread t owns node i = t>>3, 8-feature chunk c = t&7 (16B).
    // frag slot: matrix m, k-half h = c>>2, node-group g = i>>4,
    // lane sl = (c&3)*16 + (i&15); af index = (m*2+h)*2+g = varies.
    int ai = t >> 3, c = t & 7;
    int g_ = ai >> 4, lr_ = ai & 15;
    int h_ = c >> 2, lq_ = c & 3;
    int sl = lq_ * 16 + lr_;
    uint4 vx;
    if (xb) {
        vx = *(const uint4*)(xb + (size_t)node * 512 + s * 32 + c * 4);
    } else {
        const float* px = inputs + ((size_t)s * NN + node) * 64 + c * 8;
        float4 u0 = *(const float4*)(px);
        float4 u1 = *(const float4*)(px + 4);
        vx.x = pack2(u0.x, u0.y); vx.y = pack2(u0.z, u0.w);
        vx.z = pack2(u1.x, u1.y); vx.w = pack2(u1.z, u1.w);
    }
    uint4 vy = *(const uint4*)(src + (size_t)node * 512 + s * 32 + c * 4);
    __syncthreads();                       // edge cache dead; reuse LDS
    *(uint4*)&u.af[(0 + h_) * 2 + g_][sl][0] = vx;   // m=0: idx = h*2+g
    *(uint4*)&u.af[(2 + h_) * 2 + g_][sl][0] = vy;   // m=1: idx = (2+h)*2+g
    *(uint4*)&u.af[(4 + h_) * 2 + g_][sl][0] = o;    // m=2: idx = (4+h)*2+g
    __syncthreads();

    // ---- epilogue GEMM: out tile 32n x 64o, K=192; 4 waves x 2 16x16 tiles.
    int w = t >> 6, l = t & 63;
    int lr = l & 15, lq = l >> 4;
    int gg = w & 1;
    int og0 = w >> 1, og1 = 2 + (w >> 1);
    const unsigned short* wb0 = wt + (og0 * 16 + lr) * WTP + lq * 8;
    const unsigned short* wb1 = wt + (og1 * 16 + lr) * WTP + lq * 8;
    float4v acc0 = {0, 0, 0, 0}, acc1 = {0, 0, 0, 0};
    #pragma unroll
    for (int ks = 0; ks < 6; ++ks) {       // ks = m*2+h; af idx = ks*2+gg
        short8 a = *(const short8*)&u.af[ks * 2 + gg][l][0];
        short8 b0 = *(const short8*)(wb0 + ks * 32);
        short8 b1 = *(const short8*)(wb1 + ks * 32);
        acc0 = __builtin_amdgcn_mfma_f32_16x16x32_bf16(a, b0, acc0, 0, 0, 0);
        acc1 = __builtin_amdgcn_mfma_f32_16x16x32_bf16(a, b1, acc1, 0, 0, 0);
    }
    float bv0 = bias[og0 * 16 + lr], bv1 = bias[og1 * 16 + lr];
    #pragma unroll
    for (int r = 0; r < 4; ++r) {          // NN % 32 == 0: no tail check
        int n = n0 + gg * 16 + lq * 4 + r;
        float* po = out + ((size_t)s * NN + n) * 64;
        po[og0 * 16 + lr] = acc0[r] + bv0;
        po[og1 * 16 + lr] = acc1[r] + bv1;
    }
}

// fallback (no ws room for xb): gather fp32 inputs directly, emit bf16 y1
__global__ __launch_bounds__(256, 8) void spmm1_f32_k(
    const float* __restrict__ inputs, const int* __restrict__ cols,
    const float* __restrict__ vals, const int* __restrict__ rp,
    unsigned* __restrict__ y1) {
    __shared__ int2 lcv[CAP];
    int s = blockIdx.y, t = threadIdx.x;
    int n0 = blockIdx.x * 32;
    int eBase = rp[n0];
    int eCap = min(rp[n0 + 32], eBase + CAP);
    for (int i = eBase + t; i < eCap; i += 256)
        lcv[i - eBase] = make_int2(cols[i], __float_as_int(vals[i]));
    __syncthreads();

    int node = n0 + (t >> 3);
    const float* sp = inputs + (size_t)(s >> 1) * NN * 64 + (s & 1) * 32 + (t & 7) * 4;
    int e0 = rp[node], e1 = rp[node + 1];
    int eL = min(e1, eCap);
    float4 acc = make_float4(0.f, 0.f, 0.f, 0.f);
    #pragma unroll 2
    for (int e = e0; e < eL; ++e) {
        int2 cv = lcv[e - eBase];
        float v = __int_as_float(cv.y);
        float4 xv = *(const float4*)(sp + (size_t)cv.x * 64);
        acc.x += v * xv.x; acc.y += v * xv.y; acc.z += v * xv.z; acc.w += v * xv.w;
    }
    for (int e = eL; e < e1; ++e) {
        int c = cols[e]; float v = vals[e];
        float4 xv = *(const float4*)(sp + (size_t)c * 64);
        acc.x += v * xv.x; acc.y += v * xv.y; acc.z += v * xv.z; acc.w += v * xv.w;
    }
    uint2 o; o.x = pack2(acc.x, acc.y); o.y = pack2(acc.z, acc.w);
    *(uint2*)(y1 + (size_t)node * 512 + (s >> 1) * 32 + (s & 1) * 16 + (t & 7) * 2) = o;
}

extern "C" void kernel_launch(void* const* d_in, const int* in_sizes, int n_in,
                              void* d_out, int out_size, void* d_ws, size_t ws_size,
                              hipStream_t stream) {
    const float* inputs  = (const float*)d_in[0];
    const int*   sp_rows = (const int*)d_in[1];
    const int*   sp_cols = (const int*)d_in[2];
    const float* sp_vals = (const float*)d_in[3];
    const float* weight  = (const float*)d_in[4];
    const float* biases  = (const float*)d_in[5];
    float* out = (float*)d_out;

    const size_t ybytes = (size_t)NN * 512 * 4;   // 40.96 MB per bf16 matrix
    char* base = (char*)d_ws;
    unsigned* y1 = (unsigned*)base;
    size_t off = ybytes;
    const size_t tail = (((size_t)(NN + 1) * 4 + 15) & ~(size_t)15) + 64 * WTP * 2 + 64;
    bool useXb = ws_size >= 2 * ybytes + tail;
    unsigned* xb = nullptr;
    if (useXb) { xb = (unsigned*)(base + off); off += ybytes; }
    int* rp = (int*)(base + off);
    off += ((size_t)(NN + 1) * 4 + 15) & ~(size_t)15;
    unsigned short* wt = (unsigned short*)(base + off);

    if (useXb) {
        prep_k<<<10127, 256, 0, stream>>>(inputs, xb, sp_rows, rp, weight, wt, 10000);
        spmm_bf16_k<<<10000, 256, 0, stream>>>(xb, sp_cols, sp_vals, rp, y1);
    } else {
        prep_k<<<127, 256, 0, stream>>>(inputs, nullptr, sp_rows, rp, weight, wt, 0);
        spmm1_f32_k<<<dim3(625, 32), 256, 0, stream>>>(inputs, sp_cols, sp_vals, rp, y1);
    }
    spmm_gemm_k<<<10000, 256, 0, stream>>>(y1, xb, inputs, sp_cols, sp_vals, rp,
                                           wt, biases, out);
}

// Round 8
// 348.241 us; speedup vs baseline: 1.0181x; 1.0181x over previous
//
#include <hip/hip_runtime.h>

#define NN 20000   // nodes
#define EE 640000  // edges
#define CAP 2048   // LDS edge-cache (int2) = 16 KB -> no occupancy throttle
#define WTP 200    // padded k-stride of transposed weight (breaks bank conflict)

typedef __attribute__((ext_vector_type(8))) short short8;
typedef __attribute__((ext_vector_type(4))) float float4v;
typedef __attribute__((ext_vector_type(2))) float float2v;

__device__ __forceinline__ unsigned bf16rn(float x) {
    unsigned u = __float_as_uint(x);
    return (u + 0x7FFFu + ((u >> 16) & 1u)) >> 16;
}
__device__ __forceinline__ unsigned pack2(float a, float b) {
    return bf16rn(a) | (bf16rn(b) << 16);
}
__device__ __forceinline__ float bflo(unsigned u) { return __uint_as_float(u << 16); }
__device__ __forceinline__ float bfhi(unsigned u) { return __uint_as_float(u & 0xFFFF0000u); }

// Fused prep: blocks [0,nCast) cast inputs->xb; [nCast,nCast+79) rowptr;
// [nCast+79, nCast+127) weight fold. All independent -> overlap + fewer launches.
__global__ __launch_bounds__(256) void prep_k(
    const float* __restrict__ inp, unsigned* __restrict__ xb,
    const int* __restrict__ rows, int* __restrict__ rp,
    const float* __restrict__ W, unsigned short* __restrict__ wt,
    int nCast) {
    int bid = blockIdx.x, t = threadIdx.x;
    if (bid < nCast) {
        // inputs[b][n][f] fp32 -> xb[n][b*64+f] bf16; 32B in -> 16B out
        int i = bid * 256 + t;                    // over NN*128 uint4 outputs
        int n = i >> 7, c = i & 127;              // c = b*8 + f8
        int b = c >> 3, f8 = c & 7;
        const float* p = inp + ((size_t)b * NN + n) * 64 + f8 * 8;
        float4 u0 = *(const float4*)(p);
        float4 u1 = *(const float4*)(p + 4);
        uint4 o;
        o.x = pack2(u0.x, u0.y); o.y = pack2(u0.z, u0.w);
        o.z = pack2(u1.x, u1.y); o.w = pack2(u1.z, u1.w);
        *(uint4*)(xb + (size_t)n * 512 + c * 4) = o;
    } else if (bid < nCast + 79) {
        int r = (bid - nCast) * 256 + t;
        if (r > NN) return;
        int lo = 0, hi = EE;
        while (lo < hi) {
            int mid = (lo + hi) >> 1;
            if (rows[mid] < r) lo = mid + 1; else hi = mid;
        }
        rp[r] = lo;
    } else {
        // Wt[o][k'] bf16, k' = m*64+f; Chebyshev fold: m0: W0-W2, m2: 2*W2
        int i = (bid - nCast - 79) * 256 + t;
        if (i >= 64 * 192) return;
        int o = i / 192, kp = i - o * 192;
        int m = kp >> 6, f = kp & 63;
        float w = W[(f * 3 + m) * 64 + o];
        if (m == 0) w -= W[(f * 3 + 2) * 64 + o];
        else if (m == 2) w += w;
        wt[o * WTP + kp] = (unsigned short)bf16rn(w);
    }
}

__device__ __forceinline__ void accum(const uint4& q, int vbits,
                                      float2v& ac0, float2v& ac1,
                                      float2v& ac2, float2v& ac3) {
    float v_ = __int_as_float(vbits);
    float2v vv = {v_, v_};
    float2v p0 = {bflo(q.x), bfhi(q.x)};
    float2v p1 = {bflo(q.y), bfhi(q.y)};
    float2v p2 = {bflo(q.z), bfhi(q.z)};
    float2v p3 = {bflo(q.w), bfhi(q.w)};
    ac0 = __builtin_elementwise_fma(vv, p0, ac0);
    ac1 = __builtin_elementwise_fma(vv, p1, ac1);
    ac2 = __builtin_elementwise_fma(vv, p2, ac2);
    ac3 = __builtin_elementwise_fma(vv, p3, ac3);
}

// dst[n][c] = sum_e v * src[col][c], bf16 in/out.
// XCD-pinned slices: each XCD's 4MB L2 holds one 2.56MB channel-slice.
// ROOFLINE NOTE (rounds 2-5): dur invariant to VALU count (r2), unroll depth
// (r3), forced scheduling (r4); nt loads break L2 allocation (r5: FETCH
// 66->408MB, 2.4x slower). 15.6 TB/s aggregate L2 service = ~79% of random
// 64B-sector channel peak -> this loop is at the L2 ceiling. Do not touch.
__global__ __launch_bounds__(256, 8) void spmm_bf16_k(
    const unsigned* __restrict__ src, const int* __restrict__ cols,
    const float* __restrict__ vals, const int* __restrict__ rp,
    unsigned* __restrict__ dst) {
    __shared__ int2 lcv[CAP];
    int bid = blockIdx.x;
    int xcd = bid & 7, j = bid >> 3;
    int chunk = j % 625;
    int s = xcd + ((j / 625) << 3);
    int t = threadIdx.x;
    int n0 = chunk * 32;
    int eBase = rp[n0];
    int eCap = min(rp[n0 + 32], eBase + CAP);
    for (int i = eBase + t; i < eCap; i += 256)
        lcv[i - eBase] = make_int2(cols[i], __float_as_int(vals[i]));
    __syncthreads();

    int node = n0 + (t >> 3);
    unsigned tOff = (unsigned)(s * 128 + (t & 7) * 16);   // byte offset within row
    const char* sb = (const char*)src;                    // uniform SGPR base
    int e0 = rp[node], e1 = rp[node + 1];
    int eL = min(e1, eCap);
    int le = e0 - eBase, lEnd = eL - eBase;
    float2v ac0 = {0,0}, ac1 = {0,0}, ac2 = {0,0}, ac3 = {0,0};

    int e = le;
    for (; e + 4 <= lEnd; e += 4) {
        int2 c0 = lcv[e],     c1 = lcv[e + 1];
        int2 c2 = lcv[e + 2], c3 = lcv[e + 3];
        uint4 q0 = *(const uint4*)(sb + (((unsigned)c0.x << 11) + tOff));
        uint4 q1 = *(const uint4*)(sb + (((unsigned)c1.x << 11) + tOff));
        uint4 q2 = *(const uint4*)(sb + (((unsigned)c2.x << 11) + tOff));
        uint4 q3 = *(const uint4*)(sb + (((unsigned)c3.x << 11) + tOff));
        accum(q0, c0.y, ac0, ac1, ac2, ac3);
        accum(q1, c1.y, ac0, ac1, ac2, ac3);
        accum(q2, c2.y, ac0, ac1, ac2, ac3);
        accum(q3, c3.y, ac0, ac1, ac2, ac3);
    }
    for (; e < lEnd; ++e) {
        int2 cv = lcv[e];
        uint4 q = *(const uint4*)(sb + (((unsigned)cv.x << 11) + tOff));
        accum(q, cv.y, ac0, ac1, ac2, ac3);
    }
    for (int a = lEnd + eBase; a < e1; ++a) {
        int c = cols[a];
        uint4 q = *(const uint4*)(sb + (((unsigned)c << 11) + tOff));
        accum(q, __float_as_int(vals[a]), ac0, ac1, ac2, ac3);
    }
    uint4 o;
    o.x = pack2(ac0[0], ac0[1]); o.y = pack2(ac1[0], ac1[1]);
    o.z = pack2(ac2[0], ac2[1]); o.w = pack2(ac3[0], ac3[1]);
    *(uint4*)((char*)dst + (size_t)node * 2048 + tOff) = o;
}

// Fused spmm2 + GEMM: block (chunk, s) computes y2 tile = A@y1 for 32 nodes
// x batch s, keeps it in regs/LDS, then out[s][n0..)[0..64) = [x0|y1|y2]@Wt
// + bias. Deletes the y2 HBM round-trip + one launch. LDS: edge cache (16KB)
// unioned with frag-major A-tile (12KB). af 16B-unit index is XOR-swizzled
// (u' = u ^ (u>>3)): without it, lanes l and l+8 alias on ds_*_b128 -> 8-way
// conflict (r7: SQ_LDS_BANK_CONFLICT 7.08M, ~12us/CU). vx/vy issued BEFORE
// the edge loop so their HBM latency hides under it (T14).
__global__ __launch_bounds__(256, 8) void spmm_gemm_k(
    const unsigned* __restrict__ src,      // y1
    const unsigned* __restrict__ xb,       // bf16 x0 (may be null)
    const float* __restrict__ inputs,      // fp32 x0 fallback
    const int* __restrict__ cols, const float* __restrict__ vals,
    const int* __restrict__ rp, const unsigned short* __restrict__ wt,
    const float* __restrict__ bias, float* __restrict__ out) {
    __shared__ union alignas(16) {
        int2 lcv[CAP];                     // 16 KB, edge phase
        unsigned short af[12][64][8];      // 12 KB, frag-major A-tile, epilogue
    } u;
    int bid = blockIdx.x;
    int xcd = bid & 7, j = bid >> 3;
    int chunk = j % 625;
    int s = xcd + ((j / 625) << 3);
    int t = threadIdx.x;
    int n0 = chunk * 32;
    int eBase = rp[n0];
    int eCap = min(rp[n0 + 32], eBase + CAP);
    for (int i2 = eBase + t; i2 < eCap; i2 += 256)
        u.lcv[i2 - eBase] = make_int2(cols[i2], __float_as_int(vals[i2]));

    int node = n0 + (t >> 3);
    int c = t & 7;
    // issue A-tile x0/y1 loads EARLY: independent of gathers, latency hides
    // under the edge loop.
    uint4 vx, vy;
    if (xb) {
        vx = *(const uint4*)(xb + (size_t)node * 512 + s * 32 + c * 4);
    } else {
        const float* px = inputs + ((size_t)s * NN + node) * 64 + c * 8;
        float4 u0 = *(const float4*)(px);
        float4 u1 = *(const float4*)(px + 4);
        vx.x = pack2(u0.x, u0.y); vx.y = pack2(u0.z, u0.w);
        vx.z = pack2(u1.x, u1.y); vx.w = pack2(u1.z, u1.w);
    }
    vy = *(const uint4*)(src + (size_t)node * 512 + s * 32 + c * 4);
    __syncthreads();

    unsigned tOff = (unsigned)(s * 128 + (t & 7) * 16);
    const char* sb = (const char*)src;
    int e0 = rp[node], e1 = rp[node + 1];
    int eL = min(e1, eCap);
    int le = e0 - eBase, lEnd = eL - eBase;
    float2v ac0 = {0,0}, ac1 = {0,0}, ac2 = {0,0}, ac3 = {0,0};

    int e = le;
    for (; e + 4 <= lEnd; e += 4) {   // proven 4-deep edge loop (do not touch)
        int2 c0 = u.lcv[e],     c1 = u.lcv[e + 1];
        int2 c2 = u.lcv[e + 2], c3 = u.lcv[e + 3];
        uint4 q0 = *(const uint4*)(sb + (((unsigned)c0.x << 11) + tOff));
        uint4 q1 = *(const uint4*)(sb + (((unsigned)c1.x << 11) + tOff));
        uint4 q2 = *(const uint4*)(sb + (((unsigned)c2.x << 11) + tOff));
        uint4 q3 = *(const uint4*)(sb + (((unsigned)c3.x << 11) + tOff));
        accum(q0, c0.y, ac0, ac1, ac2, ac3);
        accum(q1, c1.y, ac0, ac1, ac2, ac3);
        accum(q2, c2.y, ac0, ac1, ac2, ac3);
        accum(q3, c3.y, ac0, ac1, ac2, ac3);
    }
    for (; e < lEnd; ++e) {
        int2 cv = u.lcv[e];
        uint4 q = *(const uint4*)(sb + (((unsigned)cv.x << 11) + tOff));
        accum(q, cv.y, ac0, ac1, ac2, ac3);
    }
    for (int a2 = lEnd + eBase; a2 < e1; ++a2) {
        int c2_ = cols[a2];
        uint4 q = *(const uint4*)(sb + (((unsigned)c2_ << 11) + tOff));
        accum(q, __float_as_int(vals[a2]), ac0, ac1, ac2, ac3);
    }
    uint4 o;
    o.x = pack2(ac0[0], ac0[1]); o.y = pack2(ac1[0], ac1[1]);
    o.z = pack2(ac2[0], ac2[1]); o.w = pack2(ac3[0], ac3[1]);

    // ---- stage A = [x0|y1|y2] (32 nodes x 192 bf16, batch s) in frag order.
    // thread t owns node i = t>>3, 8-feature chunk c = t&7 (16B).
    // frag slot: matrix m, k-half h = c>>2, node-group g = i>>4,
    // logical lane sl = (c&3)*16 + (i&15); PHYSICAL unit = sl ^ (sl>>3).
    int ai = t >> 3;
    int g_ = ai >> 4, lr_ = ai & 15;
    int h_ = c >> 2, lq_ = c & 3;
    int sl = lq_ * 16 + lr_;
    int slp = sl ^ (sl >> 3);              // bank-conflict swizzle
    __syncthreads();                       // edge cache dead; reuse LDS
    *(uint4*)&u.af[(0 + h_) * 2 + g_][slp][0] = vx;   // m=0
    *(uint4*)&u.af[(2 + h_) * 2 + g_][slp][0] = vy;   // m=1
    *(uint4*)&u.af[(4 + h_) * 2 + g_][slp][0] = o;    // m=2
    __syncthreads();

    // ---- epilogue GEMM: out tile 32n x 64o, K=192; 4 waves x 2 16x16 tiles.
    int w = t >> 6, l = t & 63;
    int lp = l ^ (l >> 3);                 // same swizzle on read
    int lr = l & 15, lq = l >> 4;
    int gg = w & 1;
    int og0 = w >> 1, og1 = 2 + (w >> 1);
    const unsigned short* wb0 = wt + (og0 * 16 + lr) * WTP + lq * 8;
    const unsigned short* wb1 = wt + (og1 * 16 + lr) * WTP + lq * 8;
    float4v acc0 = {0, 0, 0, 0}, acc1 = {0, 0, 0, 0};
    #pragma unroll
    for (int ks = 0; ks < 6; ++ks) {       // ks = m*2+h; af idx = ks*2+gg
        short8 a = *(const short8*)&u.af[ks * 2 + gg][lp][0];
        short8 b0 = *(const short8*)(wb0 + ks * 32);
        short8 b1 = *(const short8*)(wb1 + ks * 32);
        acc0 = __builtin_amdgcn_mfma_f32_16x16x32_bf16(a, b0, acc0, 0, 0, 0);
        acc1 = __builtin_amdgcn_mfma_f32_16x16x32_bf16(a, b1, acc1, 0, 0, 0);
    }
    float bv0 = bias[og0 * 16 + lr], bv1 = bias[og1 * 16 + lr];
    #pragma unroll
    for (int r = 0; r < 4; ++r) {          // NN % 32 == 0: no tail check
        int n = n0 + gg * 16 + lq * 4 + r;
        float* po = out + ((size_t)s * NN + n) * 64;
        po[og0 * 16 + lr] = acc0[r] + bv0;
        po[og1 * 16 + lr] = acc1[r] + bv1;
    }
}

// fallback (no ws room for xb): gather fp32 inputs directly, emit bf16 y1
__global__ __launch_bounds__(256, 8) void spmm1_f32_k(
    const float* __restrict__ inputs, const int* __restrict__ cols,
    const float* __restrict__ vals, const int* __restrict__ rp,
    unsigned* __restrict__ y1) {
    __shared__ int2 lcv[CAP];
    int s = blockIdx.y, t = threadIdx.x;
    int n0 = blockIdx.x * 32;
    int eBase = rp[n0];
    int eCap = min(rp[n0 + 32], eBase + CAP);
    for (int i = eBase + t; i < eCap; i += 256)
        lcv[i - eBase] = make_int2(cols[i], __float_as_int(vals[i]));
    __syncthreads();

    int node = n0 + (t >> 3);
    const float* sp = inputs + (size_t)(s >> 1) * NN * 64 + (s & 1) * 32 + (t & 7) * 4;
    int e0 = rp[node], e1 = rp[node + 1];
    int eL = min(e1, eCap);
    float4 acc = make_float4(0.f, 0.f, 0.f, 0.f);
    #pragma unroll 2
    for (int e = e0; e < eL; ++e) {
        int2 cv = lcv[e - eBase];
        float v = __int_as_float(cv.y);
        float4 xv = *(const float4*)(sp + (size_t)cv.x * 64);
        acc.x += v * xv.x; acc.y += v * xv.y; acc.z += v * xv.z; acc.w += v * xv.w;
    }
    for (int e = eL; e < e1; ++e) {
        int c = cols[e]; float v = vals[e];
        float4 xv = *(const float4*)(sp + (size_t)c * 64);
        acc.x += v * xv.x; acc.y += v * xv.y; acc.z += v * xv.z; acc.w += v * xv.w;
    }
    uint2 o; o.x = pack2(acc.x, acc.y); o.y = pack2(acc.z, acc.w);
    *(uint2*)(y1 + (size_t)node * 512 + (s >> 1) * 32 + (s & 1) * 16 + (t & 7) * 2) = o;
}

extern "C" void kernel_launch(void* const* d_in, const int* in_sizes, int n_in,
                              void* d_out, int out_size, void* d_ws, size_t ws_size,
                              hipStream_t stream) {
    const float* inputs  = (const float*)d_in[0];
    const int*   sp_rows = (const int*)d_in[1];
    const int*   sp_cols = (const int*)d_in[2];
    const float* sp_vals = (const float*)d_in[3];
    const float* weight  = (const float*)d_in[4];
    const float* biases  = (const float*)d_in[5];
    float* out = (float*)d_out;

    const size_t ybytes = (size_t)NN * 512 * 4;   // 40.96 MB per bf16 matrix
    char* base = (char*)d_ws;
    unsigned* y1 = (unsigned*)base;
    size_t off = ybytes;
    const size_t tail = (((size_t)(NN + 1) * 4 + 15) & ~(size_t)15) + 64 * WTP * 2 + 64;
    bool useXb = ws_size >= 2 * ybytes + tail;
    unsigned* xb = nullptr;
    if (useXb) { xb = (unsigned*)(base + off); off += ybytes; }
    int* rp = (int*)(base + off);
    off += ((size_t)(NN + 1) * 4 + 15) & ~(size_t)15;
    unsigned short* wt = (unsigned short*)(base + off);

    if (useXb) {
        prep_k<<<10127, 256, 0, stream>>>(inputs, xb, sp_rows, rp, weight, wt, 10000);
        spmm_bf16_k<<<10000, 256, 0, stream>>>(xb, sp_cols, sp_vals, rp, y1);
    } else {
        prep_k<<<127, 256, 0, stream>>>(inputs, nullptr, sp_rows, rp, weight, wt, 0);
        spmm1_f32_k<<<dim3(625, 32), 256, 0, stream>>>(inputs, sp_cols, sp_vals, rp, y1);
    }
    spmm_gemm_k<<<10000, 256, 0, stream>>>(y1, xb, inputs, sp_cols, sp_vals, rp,
                                           wt, biases, out);
}